// Round 13
// baseline (287.831 us; speedup 1.0000x reference)
//
#include <hip/hip_runtime.h>
#include <hip/hip_bf16.h>
#include <stdint.h>

#define B_ 8
#define N_ 2048
#define F_ 64
#define FH_ 64
#define H_ 4
#define C_ (H_*FH_)
#define CHUNK 64
#define NCHUNK (N_/CHUNK)
#define LOG2E 1.44269504088896340736f

typedef short short8 __attribute__((ext_vector_type(8)));   // 8 bf16 raw bits (4 VGPRs)
typedef float f32x4 __attribute__((ext_vector_type(4)));

// wait until at most N VMEM ops outstanding (no exp/lgkm wait). gfx9 encoding:
// vmcnt[3:0]=bits3:0, expcnt=bits6:4, lgkmcnt=bits11:8, vmcnt[5:4]=bits15:14.
#define WAITVM(N) __builtin_amdgcn_s_waitcnt(((N)&15) | (7<<4) | (15<<8) | ((((N)>>4)&3)<<14))

// float -> bf16 raw bits (RNE)
__device__ __forceinline__ short f2bf(float f) {
    __hip_bfloat16 h = __float2bfloat16(f);
    return __builtin_bit_cast(short, h);
}

// async global->LDS DMA (the only prefetch the compiler cannot sink: R7-R11)
__device__ __forceinline__ void async16(void* l, const void* g) {
    __builtin_amdgcn_global_load_lds((const __attribute__((address_space(1))) unsigned int*)g,
                                     (__attribute__((address_space(3))) unsigned int*)l, 16, 0, 0);
}
__device__ __forceinline__ void async4(void* l, const void* g) {
    __builtin_amdgcn_global_load_lds((const __attribute__((address_space(1))) unsigned int*)g,
                                     (__attribute__((address_space(3))) unsigned int*)l, 4, 0, 0);
}

// ---------------- K0: WT[h][o][f] = bf16(W[h][f][o]) ----------------
__global__ __launch_bounds__(256) void k0_wt(const float* __restrict__ W,
                                             __hip_bfloat16* __restrict__ WT) {
    int idx = blockIdx.x * 256 + threadIdx.x;   // 16384 elems total
    int h = idx >> 12, rem = idx & 4095, o = rem >> 6, f = rem & 63;
    WT[idx] = __float2bfloat16(W[(h * F_ + f) * FH_ + o]);
}

// ---------------- KP: pack A (fp32 {0,1}) into a bitmask, 1 bit/edge ----------------
__global__ __launch_bounds__(256) void kp_pack(const float* __restrict__ A,
                                               unsigned long long* __restrict__ Amask) {
    const int wave = threadIdx.x >> 6, lane = threadIdx.x & 63;
    const int R = blockIdx.x * 4 + wave;        // global row 0..16383 (= b*N + i)
    const float* arow = A + (size_t)R * N_;
    unsigned long long* mrow = Amask + (size_t)R * (N_ / 64);
#pragma unroll
    for (int i = 0; i < 8; ++i) {               // 8 x 256 cols
        float a0 = arow[i * 256 + lane];
        float a1 = arow[i * 256 + 64 + lane];
        float a2 = arow[i * 256 + 128 + lane];
        float a3 = arow[i * 256 + 192 + lane];
        unsigned long long m0 = __ballot(a0 != 0.0f);
        unsigned long long m1 = __ballot(a1 != 0.0f);
        unsigned long long m2 = __ballot(a2 != 0.0f);
        unsigned long long m3 = __ballot(a3 != 0.0f);
        if (lane == 0) {
            mrow[i * 4 + 0] = m0; mrow[i * 4 + 1] = m1;
            mrow[i * 4 + 2] = m2; mrow[i * 4 + 3] = m3;
        }
    }
}

// ---------------- K1: featsT = (X@W)^T via MFMA, fused ss/sn epilogue ----------------
__global__ __launch_bounds__(256) void k1_feats(const float* __restrict__ X,
                                                const __hip_bfloat16* __restrict__ WT,
                                                const float* __restrict__ a_self,
                                                const float* __restrict__ a_neigh,
                                                __hip_bfloat16* __restrict__ featsT,
                                                float* __restrict__ ss,
                                                float* __restrict__ sn) {
    __shared__ float a_lds[2][FH_];
    __shared__ __hip_bfloat16 c_lds[FH_ * 72];  // padded leading dim 72 vs 64
    const int nb = blockIdx.x, h = blockIdx.y, b = blockIdx.z;
    const int tid = threadIdx.x;
    if (tid < 64)       a_lds[0][tid] = a_self[h * FH_ + tid];
    else if (tid < 128) a_lds[1][tid - 64] = a_neigh[h * FH_ + tid - 64];
    __syncthreads();

    const int wave = tid >> 6, lane = tid & 63;
    const int m = lane & 15, q = lane >> 4;
    const int nl = wave * 16 + m;               // local column 0..63
    const int n = nb * 64 + nl;                 // B-frag column (node index)
    f32x4 acc[4] = {};
#pragma unroll
    for (int ks = 0; ks < 2; ++ks) {            // K = F = 64, two steps of 32
        const float* xp = X + ((size_t)(b * N_ + n)) * F_ + ks * 32 + q * 8;
        float4 x0 = *(const float4*)xp;
        float4 x1 = *(const float4*)(xp + 4);
        short8 bfrag;
        bfrag[0] = f2bf(x0.x); bfrag[1] = f2bf(x0.y);
        bfrag[2] = f2bf(x0.z); bfrag[3] = f2bf(x0.w);
        bfrag[4] = f2bf(x1.x); bfrag[5] = f2bf(x1.y);
        bfrag[6] = f2bf(x1.z); bfrag[7] = f2bf(x1.w);
#pragma unroll
        for (int ot = 0; ot < 4; ++ot) {
            short8 afrag = *(const short8*)(WT + ((size_t)(h * FH_ + ot * 16 + m)) * F_ + ks * 32 + q * 8);
            acc[ot] = __builtin_amdgcn_mfma_f32_16x16x32_bf16(afrag, bfrag, acc[ot], 0, 0, 0);
        }
    }
    float ssv = 0.f, snv = 0.f;
#pragma unroll
    for (int ot = 0; ot < 4; ++ot) {
#pragma unroll
        for (int r = 0; r < 4; ++r) {
            int orow = ot * 16 + q * 4 + r;     // C: row=(lane>>4)*4+r, col=lane&15
            float v = acc[ot][r];
            c_lds[orow * 72 + nl] = __float2bfloat16(v);
            ssv += v * a_lds[0][orow];
            snv += v * a_lds[1][orow];
        }
    }
    ssv += __shfl_xor(ssv, 16); ssv += __shfl_xor(ssv, 32);
    snv += __shfl_xor(snv, 16); snv += __shfl_xor(snv, 32);
    __syncthreads();
    {   // coalesced featsT store
        int o = tid >> 2, c = (tid & 3) * 16;
        const __hip_bfloat16* src = c_lds + o * 72 + c;
        __hip_bfloat16* dst = featsT + ((size_t)(b * H_ + h) * FH_ + o) * N_ + nb * 64 + c;
        *(uint4*)dst       = *(const uint4*)src;
        *(uint4*)(dst + 8) = *(const uint4*)(src + 8);
    }
    if (lane < 16) {
        size_t idx = ((size_t)(b * H_ + h)) * N_ + n;
        ss[idx] = ssv * LOG2E;
        sn[idx] = snv * LOG2E;
    }
}

// ---------------- K3: barrier-free per-wave DMA pipeline ----------------
// grid (N/64, H, B) = 1024 blocks; block = 1 head, 64 rows. Wave = (rowhalf rh,
// feathalf fh): 32 rows x 32 feats, staging is WAVE-PRIVATE (fv 4 KB + mask 256 B
// per chunk, double-buffered) -> NO __syncthreads in the K-loop. Pipeline: issue
// 5 DMAs for chunk c+1, s_waitcnt vmcnt(5) waits exactly for chunk c's 5 oldest
// (m135 semantics), sched_barrier pins ds_reads after the wait. This removes the
// block rendezvous + vmcnt(0) drain that made R11/R12 identical at ~52 us.
// Cost: P computed twice (once per feathalf). LDS 50 KB -> 3 blocks/CU.
__global__ __launch_bounds__(256, 3) void k3_attn(const unsigned int* __restrict__ Amask,
                                                  const __hip_bfloat16* __restrict__ featsT,
                                                  const float* __restrict__ ss,
                                                  const float* __restrict__ sn,
                                                  const float* __restrict__ bias,
                                                  float* __restrict__ out) {
    __shared__ __hip_bfloat16 fv_lds[4][2][32 * CHUNK];    // 4 waves x dbuf x 4 KB
    __shared__ unsigned int   mk_lds[4][2][64];            // 4 waves x dbuf x 256 B
    __shared__ float e1_lds[N_];                           // 8 KB: 2^sn_j
    __shared__ float e2_lds[N_];                           // 8 KB: 2^(0.2 sn_j)

    const int tile = blockIdx.x, h = blockIdx.y, b = blockIdx.z;
    const int tid = threadIdx.x, wave = tid >> 6, lane = tid & 63;
    const int m = lane & 15, q = lane >> 4;
    const int rh = wave >> 1;                   // row half: rows rh*32 .. +32
    const int fh = wave & 1;                    // feat half: feats fh*32 .. +32
    const int rowtile = tile * 64;

    {   // e-tables: 512 float4 slots, 2 per thread (one barrier, init only)
        const float4* snrow = (const float4*)(sn + ((size_t)(b * H_ + h)) * N_);
        float4* e1v = (float4*)e1_lds;
        float4* e2v = (float4*)e2_lds;
#pragma unroll
        for (int i = 0; i < 2; ++i) {
            int idx = tid + i * 256;
            float4 v = snrow[idx];
            float4 u1, u2;
            u1.x = exp2f(v.x); u1.y = exp2f(v.y); u1.z = exp2f(v.z); u1.w = exp2f(v.w);
            u2.x = exp2f(0.2f * v.x); u2.y = exp2f(0.2f * v.y);
            u2.z = exp2f(0.2f * v.z); u2.w = exp2f(0.2f * v.w);
            e1v[idx] = u1; e2v[idx] = u2;
        }
    }
    // per-sub-tile self scores (2 sub-tiles of 16 rows within this wave's 32)
    const size_t srow = ((size_t)(b * H_ + h)) * N_ + rowtile + rh * 32 + m;
    const float ssi0 = ss[srow], ssi1 = ss[srow + 16];
    const float e1i[2] = {exp2f(ssi0), exp2f(ssi1)};
    const float e2i[2] = {exp2f(0.2f * ssi0), exp2f(0.2f * ssi1)};

    const __hip_bfloat16* fhead = featsT + (((size_t)(b * H_ + h)) * FH_ + fh * 32) * N_;
    const unsigned int* mbase = Amask + ((size_t)(b * N_) + rowtile + rh * 32) * (N_ / 32);

    __hip_bfloat16* fvw[2] = {&fv_lds[wave][0][0], &fv_lds[wave][1][0]};
    unsigned int*   mkw[2] = {&mk_lds[wave][0][0], &mk_lds[wave][1][0]};

    // stage chunk c into this wave's private buffer bufi: 4 fv issues + 1 mask issue
    auto stage = [&](int c, int bufi) {
        const int cb = c * CHUNK;
#pragma unroll
        for (int i = 0; i < 4; ++i) {           // fv: 32 feats x 64 cols = 256 16B-units
            int unit = i * 64 + lane;
            int o = unit >> 3, v = unit & 7;
            int u = v ^ (o & 7);                // XOR swizzle
            async16(fvw[bufi] + (size_t)(i * 64) * 8, fhead + (size_t)o * N_ + cb + u * 8);
        }
        {                                       // mask: 32 rows x 2 dwords = 64 units
            int row = lane >> 1, dw = lane & 1;
            async4(mkw[bufi], mbase + (size_t)row * (N_ / 32) + (cb >> 5) + dw);
        }
    };

    stage(0, 0);
    __syncthreads();    // e-tables visible to all waves (also covers stage(0) via drain)

    f32x4 acc[2][2] = {};       // [sub-tile st][ctl]
    f32x4 accl[2] = {};         // row sums per sub-tile
    short8 ones;
#pragma unroll
    for (int s = 0; s < 8; ++s) ones[s] = (short)0x3F80;   // bf16 1.0

    auto compute = [&](int c, int cur) {
        const int cg = c * CHUNK;
        // e-tables (broadcast within q-group)
        float4 eA10 = *(const float4*)(e1_lds + cg + q * 8);
        float4 eA11 = *(const float4*)(e1_lds + cg + q * 8 + 4);
        float4 eB10 = *(const float4*)(e1_lds + cg + 32 + q * 8);
        float4 eB11 = *(const float4*)(e1_lds + cg + 32 + q * 8 + 4);
        float4 eA20 = *(const float4*)(e2_lds + cg + q * 8);
        float4 eA21 = *(const float4*)(e2_lds + cg + q * 8 + 4);
        float4 eB20 = *(const float4*)(e2_lds + cg + 32 + q * 8);
        float4 eB21 = *(const float4*)(e2_lds + cg + 32 + q * 8 + 4);
        // fv fragments from private LDS: chain A = col-units 0..3, B = 4..7
        short8 fA[2], fB[2];
#pragma unroll
        for (int ctl = 0; ctl < 2; ++ctl) {
            int o = ctl * 16 + m;               // local feat 0..31
            fA[ctl] = *(const short8*)(fvw[cur] + ((o << 3) + (q ^ (o & 7))) * 8);
            fB[ctl] = *(const short8*)(fvw[cur] + ((o << 3) + ((4 + q) ^ (o & 7))) * 8);
        }
        float e1A[8] = {eA10.x, eA10.y, eA10.z, eA10.w, eA11.x, eA11.y, eA11.z, eA11.w};
        float e1B[8] = {eB10.x, eB10.y, eB10.z, eB10.w, eB11.x, eB11.y, eB11.z, eB11.w};
        float e2A[8] = {eA20.x, eA20.y, eA20.z, eA20.w, eA21.x, eA21.y, eA21.z, eA21.w};
        float e2B[8] = {eB20.x, eB20.y, eB20.z, eB20.w, eB21.x, eB21.y, eB21.z, eB21.w};

#pragma unroll
        for (int st = 0; st < 2; ++st) {
            unsigned int mA = mkw[cur][(st * 16 + m) * 2];
            unsigned int mB = mkw[cur][(st * 16 + m) * 2 + 1];
            short8 pA, pB;
#pragma unroll
            for (int s = 0; s < 8; ++s) {
                // exp2(leaky(si+sj)) = max(e1i*e1j, e2i*e2j); adjacency via bit test
                float vA = fmaxf(e1i[st] * e1A[s], e2i[st] * e2A[s]);
                float vB = fmaxf(e1i[st] * e1B[s], e2i[st] * e2B[s]);
                const int bit = q * 8 + s;
                pA[s] = (mA >> bit) & 1 ? f2bf(vA) : (short)0;
                pB[s] = (mB >> bit) & 1 ? f2bf(vB) : (short)0;
            }
#pragma unroll
            for (int ctl = 0; ctl < 2; ++ctl) {
                acc[st][ctl] = __builtin_amdgcn_mfma_f32_16x16x32_bf16(pA, fA[ctl], acc[st][ctl], 0, 0, 0);
                acc[st][ctl] = __builtin_amdgcn_mfma_f32_16x16x32_bf16(pB, fB[ctl], acc[st][ctl], 0, 0, 0);
            }
            accl[st] = __builtin_amdgcn_mfma_f32_16x16x32_bf16(pA, ones, accl[st], 0, 0, 0);
            accl[st] = __builtin_amdgcn_mfma_f32_16x16x32_bf16(pB, ones, accl[st], 0, 0, 0);
        }
    };

    for (int c = 0; c < NCHUNK - 1; ++c) {
        stage(c + 1, (c + 1) & 1);              // 5 new DMAs (newest)
        WAITVM(5);                              // wait for chunk c's 5 (oldest)
        __builtin_amdgcn_sched_barrier(0);      // pin: no ds_read hoists above the wait
        compute(c, c & 1);
    }
    WAITVM(0);
    __builtin_amdgcn_sched_barrier(0);
    compute(NCHUNK - 1, (NCHUNK - 1) & 1);

    float bc[2];
#pragma unroll
    for (int ctl = 0; ctl < 2; ++ctl) bc[ctl] = bias[h * FH_ + fh * 32 + ctl * 16 + m];

#pragma unroll
    for (int st = 0; st < 2; ++st) {
#pragma unroll
        for (int r = 0; r < 4; ++r) {
            float inv = 1.0f / accl[st][r];     // row sum (all cols identical)
            int gr = rowtile + rh * 32 + st * 16 + q * 4 + r;
#pragma unroll
            for (int ctl = 0; ctl < 2; ++ctl) {
                float v = acc[st][ctl][r] * inv + bc[ctl];
                out[((size_t)(b * N_) + gr) * C_ + h * FH_ + fh * 32 + ctl * 16 + m] = fmaxf(v, 0.0f);
            }
        }
    }
}

extern "C" void kernel_launch(void* const* d_in, const int* in_sizes, int n_in,
                              void* d_out, int out_size, void* d_ws, size_t ws_size,
                              hipStream_t stream) {
    const float* X       = (const float*)d_in[0];
    const float* A       = (const float*)d_in[1];
    const float* W       = (const float*)d_in[2];
    const float* bias    = (const float*)d_in[3];
    const float* a_self  = (const float*)d_in[4];
    const float* a_neigh = (const float*)d_in[5];
    float* out = (float*)d_out;   // reference output dtype is float32

    char* ws = (char*)d_ws;
    __hip_bfloat16* featsT = (__hip_bfloat16*)(ws);             // 8 MB   [B][H][FH][N]
    __hip_bfloat16* WT     = (__hip_bfloat16*)(ws + 8388608);   // 32 KB  [H][FH][F]
    float* ss              = (float*)(ws + 8421376);            // 256 KB [B][H][N]
    float* sn              = (float*)(ws + 8683520);            // 256 KB [B][H][N]
    unsigned long long* Am = (unsigned long long*)(ws + 8945664); // 4 MB bitmask

    k0_wt    <<<64, 256, 0, stream>>>(W, WT);
    kp_pack  <<<B_ * N_ / 4, 256, 0, stream>>>(A, Am);
    k1_feats <<<dim3(N_ / 64, H_, B_), 256, 0, stream>>>(X, WT, a_self, a_neigh, featsT, ss, sn);
    k3_attn  <<<dim3(N_ / 64, H_, B_), 256, 0, stream>>>((const unsigned int*)Am, featsT, ss, sn, bias, out);
}

// Round 14
// 276.155 us; speedup vs baseline: 1.0423x; 1.0423x over previous
//
#include <hip/hip_runtime.h>
#include <hip/hip_bf16.h>
#include <stdint.h>

#define B_ 8
#define N_ 2048
#define F_ 64
#define FH_ 64
#define H_ 4
#define C_ (H_*FH_)
#define CHUNK 64
#define NCHUNK (N_/CHUNK)
#define LOG2E 1.44269504088896340736f

typedef short short8 __attribute__((ext_vector_type(8)));   // 8 bf16 raw bits (4 VGPRs)
typedef float f32x4 __attribute__((ext_vector_type(4)));
typedef int   i32x4 __attribute__((ext_vector_type(4)));

// wait until at most N VMEM ops outstanding (no exp/lgkm wait). gfx9 encoding:
// vmcnt[3:0]=bits3:0, expcnt=bits6:4, lgkmcnt=bits11:8, vmcnt[5:4]=bits15:14.
#define WAITVM(N) __builtin_amdgcn_s_waitcnt(((N)&15) | (7<<4) | (15<<8) | ((((N)>>4)&3)<<14))

// float -> bf16 raw bits (RNE)
__device__ __forceinline__ short f2bf(float f) {
    __hip_bfloat16 h = __float2bfloat16(f);
    return __builtin_bit_cast(short, h);
}

// async global->LDS DMA (the only prefetch the compiler cannot sink: R7-R11)
__device__ __forceinline__ void async16(void* l, const void* g) {
    __builtin_amdgcn_global_load_lds((const __attribute__((address_space(1))) unsigned int*)g,
                                     (__attribute__((address_space(3))) unsigned int*)l, 16, 0, 0);
}
__device__ __forceinline__ void async4(void* l, const void* g) {
    __builtin_amdgcn_global_load_lds((const __attribute__((address_space(1))) unsigned int*)g,
                                     (__attribute__((address_space(3))) unsigned int*)l, 4, 0, 0);
}

// ---------------- K0: WT[h][o][f] = bf16(W[h][f][o]) ----------------
__global__ __launch_bounds__(256) void k0_wt(const float* __restrict__ W,
                                             __hip_bfloat16* __restrict__ WT) {
    int idx = blockIdx.x * 256 + threadIdx.x;   // 16384 elems total
    int h = idx >> 12, rem = idx & 4095, o = rem >> 6, f = rem & 63;
    WT[idx] = __float2bfloat16(W[(h * F_ + f) * FH_ + o]);
}

// ---------------- KP: pack A (fp32 {0,1}) into a bitmask, 1 bit/edge ----------------
__global__ __launch_bounds__(256) void kp_pack(const float* __restrict__ A,
                                               unsigned long long* __restrict__ Amask) {
    const int wave = threadIdx.x >> 6, lane = threadIdx.x & 63;
    const int R = blockIdx.x * 4 + wave;        // global row 0..16383 (= b*N + i)
    const float* arow = A + (size_t)R * N_;
    unsigned long long* mrow = Amask + (size_t)R * (N_ / 64);
#pragma unroll
    for (int i = 0; i < 8; ++i) {               // 8 x 256 cols
        float a0 = arow[i * 256 + lane];
        float a1 = arow[i * 256 + 64 + lane];
        float a2 = arow[i * 256 + 128 + lane];
        float a3 = arow[i * 256 + 192 + lane];
        unsigned long long m0 = __ballot(a0 != 0.0f);
        unsigned long long m1 = __ballot(a1 != 0.0f);
        unsigned long long m2 = __ballot(a2 != 0.0f);
        unsigned long long m3 = __ballot(a3 != 0.0f);
        if (lane == 0) {
            mrow[i * 4 + 0] = m0; mrow[i * 4 + 1] = m1;
            mrow[i * 4 + 2] = m2; mrow[i * 4 + 3] = m3;
        }
    }
}

// ---------------- K1: featsT = (X@W)^T via MFMA, fused ss/sn epilogue ----------------
__global__ __launch_bounds__(256) void k1_feats(const float* __restrict__ X,
                                                const __hip_bfloat16* __restrict__ WT,
                                                const float* __restrict__ a_self,
                                                const float* __restrict__ a_neigh,
                                                __hip_bfloat16* __restrict__ featsT,
                                                float* __restrict__ ss,
                                                float* __restrict__ sn) {
    __shared__ float a_lds[2][FH_];
    __shared__ __hip_bfloat16 c_lds[FH_ * 72];  // padded leading dim 72 vs 64
    const int nb = blockIdx.x, h = blockIdx.y, b = blockIdx.z;
    const int tid = threadIdx.x;
    if (tid < 64)       a_lds[0][tid] = a_self[h * FH_ + tid];
    else if (tid < 128) a_lds[1][tid - 64] = a_neigh[h * FH_ + tid - 64];
    __syncthreads();

    const int wave = tid >> 6, lane = tid & 63;
    const int m = lane & 15, q = lane >> 4;
    const int nl = wave * 16 + m;               // local column 0..63
    const int n = nb * 64 + nl;                 // B-frag column (node index)
    f32x4 acc[4] = {};
#pragma unroll
    for (int ks = 0; ks < 2; ++ks) {            // K = F = 64, two steps of 32
        const float* xp = X + ((size_t)(b * N_ + n)) * F_ + ks * 32 + q * 8;
        float4 x0 = *(const float4*)xp;
        float4 x1 = *(const float4*)(xp + 4);
        short8 bfrag;
        bfrag[0] = f2bf(x0.x); bfrag[1] = f2bf(x0.y);
        bfrag[2] = f2bf(x0.z); bfrag[3] = f2bf(x0.w);
        bfrag[4] = f2bf(x1.x); bfrag[5] = f2bf(x1.y);
        bfrag[6] = f2bf(x1.z); bfrag[7] = f2bf(x1.w);
#pragma unroll
        for (int ot = 0; ot < 4; ++ot) {
            short8 afrag = *(const short8*)(WT + ((size_t)(h * FH_ + ot * 16 + m)) * F_ + ks * 32 + q * 8);
            acc[ot] = __builtin_amdgcn_mfma_f32_16x16x32_bf16(afrag, bfrag, acc[ot], 0, 0, 0);
        }
    }
    float ssv = 0.f, snv = 0.f;
#pragma unroll
    for (int ot = 0; ot < 4; ++ot) {
#pragma unroll
        for (int r = 0; r < 4; ++r) {
            int orow = ot * 16 + q * 4 + r;     // C: row=(lane>>4)*4+r, col=lane&15
            float v = acc[ot][r];
            c_lds[orow * 72 + nl] = __float2bfloat16(v);
            ssv += v * a_lds[0][orow];
            snv += v * a_lds[1][orow];
        }
    }
    ssv += __shfl_xor(ssv, 16); ssv += __shfl_xor(ssv, 32);
    snv += __shfl_xor(snv, 16); snv += __shfl_xor(snv, 32);
    __syncthreads();
    {   // coalesced featsT store
        int o = tid >> 2, c = (tid & 3) * 16;
        const __hip_bfloat16* src = c_lds + o * 72 + c;
        __hip_bfloat16* dst = featsT + ((size_t)(b * H_ + h) * FH_ + o) * N_ + nb * 64 + c;
        *(uint4*)dst       = *(const uint4*)src;
        *(uint4*)(dst + 8) = *(const uint4*)(src + 8);
    }
    if (lane < 16) {
        size_t idx = ((size_t)(b * H_ + h)) * N_ + n;
        ss[idx] = ssv * LOG2E;
        sn[idx] = snv * LOG2E;
    }
}

// ---------------- K3: drain-free shared-tile DMA pipeline ----------------
// grid (N/64, H, B) = 1024 blocks; block = 1 head, 64 rows; wave owns 16 rows x
// ALL 64 feats (P computed once -- R13's feat-split doubled it). fv tile is
// block-shared, staged PARTITIONED (each wave 1/4) and triple-buffered; per chunk:
// each wave issues its 3 DMAs, computes, WAITVM(3) (waits only its own oldest 3),
// then RAW s_barrier (no vmcnt(0) drain -- the drain was R11/R12's 52 us plateau).
// Triple buffer is required: within one barrier window stage(c+2) and compute(c)
// coexist, (c+2)%3 != c%3. P uses bit-trick bf16: +0x8000 round, sext-bit mask
// (v_bfe_i32+v_and), v_perm_b32 pack -- ~6 VALU/elem vs ~15 for cvt+insert.
__global__ __launch_bounds__(256, 3) void k3_attn(const unsigned int* __restrict__ Amask,
                                                  const __hip_bfloat16* __restrict__ featsT,
                                                  const float* __restrict__ ss,
                                                  const float* __restrict__ sn,
                                                  const float* __restrict__ bias,
                                                  float* __restrict__ out) {
    __shared__ __attribute__((aligned(16))) __hip_bfloat16 fv_lds[3][64 * CHUNK]; // 3 x 8 KB
    __shared__ __attribute__((aligned(16))) unsigned int   mk_lds[3][128];        // 3 x 512 B
    __shared__ __attribute__((aligned(16))) float e1_lds[N_];                     // 8 KB
    __shared__ __attribute__((aligned(16))) float e2_lds[N_];                     // 8 KB

    const int tile = blockIdx.x, h = blockIdx.y, b = blockIdx.z;
    const int tid = threadIdx.x, wave = tid >> 6, lane = tid & 63;
    const int m = lane & 15, q = lane >> 4;
    const int rowtile = tile * 64;

    const __hip_bfloat16* fhead = featsT + ((size_t)(b * H_ + h)) * FH_ * N_;
    const unsigned int* mbase = Amask + ((size_t)(b * N_) + rowtile) * (N_ / 32);

    // stage chunk c into buffer bufi: exactly 3 DMA issues per wave (uniform vmcnt).
    auto stage = [&](int c, int bufi) {
        const int cb = c * CHUNK;
#pragma unroll
        for (int i = 0; i < 2; ++i) {           // fv: wave w covers slots w*128..+127
            int base_slot = wave * 128 + i * 64;
            int slot = base_slot + lane;
            int o = slot >> 3, vs = slot & 7;
            int ug = vs ^ (o & 7);              // XOR swizzle: slot holds col-unit ug
            async16(&fv_lds[bufi][base_slot * 8], fhead + (size_t)o * N_ + cb + ug * 8);
        }
        {                                       // mask: 128 dwords; waves 2,3 duplicate 0,1
            int base_slot = (wave & 1) * 64;
            int slot = base_slot + lane;
            int row = slot >> 1, dw = slot & 1;
            async4(&mk_lds[bufi][base_slot], mbase + (size_t)row * (N_ / 32) + (cb >> 5) + dw);
        }
    };

    stage(0, 0);
    stage(1, 1);

    {   // e-tables: 512 float4 slots, 2 per thread
        const float4* snrow = (const float4*)(sn + ((size_t)(b * H_ + h)) * N_);
        float4* e1v = (float4*)e1_lds;
        float4* e2v = (float4*)e2_lds;
#pragma unroll
        for (int i = 0; i < 2; ++i) {
            int idx = tid + i * 256;
            float4 v = snrow[idx];
            float4 u1, u2;
            u1.x = exp2f(v.x); u1.y = exp2f(v.y); u1.z = exp2f(v.z); u1.w = exp2f(v.w);
            u2.x = exp2f(0.2f * v.x); u2.y = exp2f(0.2f * v.y);
            u2.z = exp2f(0.2f * v.z); u2.w = exp2f(0.2f * v.w);
            e1v[idx] = u1; e2v[idx] = u2;
        }
    }
    const float ssi = ss[((size_t)(b * H_ + h)) * N_ + rowtile + wave * 16 + m];
    const float e1i = exp2f(ssi), e2i = exp2f(0.2f * ssi);

    __syncthreads();    // init-only: drains stage(0)+stage(1) DMA and e-table writes

    f32x4 acc[2][4] = {};       // [chain][ct]
    f32x4 accl[2] = {};
    short8 ones;
#pragma unroll
    for (int s = 0; s < 8; ++s) ones[s] = (short)0x3F80;   // bf16 1.0

    auto compute = [&](int c, int cur) {
        const int cg = c * CHUNK;
        float4 eA10 = *(const float4*)(e1_lds + cg + q * 8);
        float4 eA11 = *(const float4*)(e1_lds + cg + q * 8 + 4);
        float4 eB10 = *(const float4*)(e1_lds + cg + 32 + q * 8);
        float4 eB11 = *(const float4*)(e1_lds + cg + 32 + q * 8 + 4);
        float4 eA20 = *(const float4*)(e2_lds + cg + q * 8);
        float4 eA21 = *(const float4*)(e2_lds + cg + q * 8 + 4);
        float4 eB20 = *(const float4*)(e2_lds + cg + 32 + q * 8);
        float4 eB21 = *(const float4*)(e2_lds + cg + 32 + q * 8 + 4);
        short8 fA[4], fB[4];
#pragma unroll
        for (int ct = 0; ct < 4; ++ct) {        // swizzled: slot = o*8 + (u ^ (o&7))
            int o = ct * 16 + m;
            fA[ct] = *(const short8*)(fv_lds[cur] + ((o << 3) + (q ^ (o & 7))) * 8);
            fB[ct] = *(const short8*)(fv_lds[cur] + ((o << 3) + ((4 + q) ^ (o & 7))) * 8);
        }
        uint2 md = *(const uint2*)&mk_lds[cur][(wave * 16 + m) * 2];
        unsigned int mAq = md.x >> (q * 8);
        unsigned int mBq = md.y >> (q * 8);

        float e1A[8] = {eA10.x, eA10.y, eA10.z, eA10.w, eA11.x, eA11.y, eA11.z, eA11.w};
        float e1B[8] = {eB10.x, eB10.y, eB10.z, eB10.w, eB11.x, eB11.y, eB11.z, eB11.w};
        float e2A[8] = {eA20.x, eA20.y, eA20.z, eA20.w, eA21.x, eA21.y, eA21.z, eA21.w};
        float e2B[8] = {eB20.x, eB20.y, eB20.z, eB20.w, eB21.x, eB21.y, eB21.z, eB21.w};

        unsigned int uA[8], uB[8];
#pragma unroll
        for (int s = 0; s < 8; ++s) {
            // exp2(leaky(si+sj)) = max(e1i*e1j, e2i*e2j); bf16 via +0x8000 round;
            // mask via sign-extended bit (v_bfe_i32) AND.
            float vA = fmaxf(e1i * e1A[s], e2i * e2A[s]);
            float vB = fmaxf(e1i * e1B[s], e2i * e2B[s]);
            int selA = ((int)(mAq << (31 - s))) >> 31;
            int selB = ((int)(mBq << (31 - s))) >> 31;
            uA[s] = (__float_as_uint(vA) + 0x8000u) & (unsigned int)selA;
            uB[s] = (__float_as_uint(vB) + 0x8000u) & (unsigned int)selB;
        }
        i32x4 wa, wb;
#pragma unroll
        for (int d = 0; d < 4; ++d) {           // pack two bf16 per dword: one v_perm each
            wa[d] = (int)__builtin_amdgcn_perm(uA[2 * d + 1], uA[2 * d], 0x07060302u);
            wb[d] = (int)__builtin_amdgcn_perm(uB[2 * d + 1], uB[2 * d], 0x07060302u);
        }
        short8 pA = __builtin_bit_cast(short8, wa);
        short8 pB = __builtin_bit_cast(short8, wb);

#pragma unroll
        for (int ct = 0; ct < 4; ++ct) {
            acc[0][ct] = __builtin_amdgcn_mfma_f32_16x16x32_bf16(pA, fA[ct], acc[0][ct], 0, 0, 0);
            acc[1][ct] = __builtin_amdgcn_mfma_f32_16x16x32_bf16(pB, fB[ct], acc[1][ct], 0, 0, 0);
        }
        accl[0] = __builtin_amdgcn_mfma_f32_16x16x32_bf16(pA, ones, accl[0], 0, 0, 0);
        accl[1] = __builtin_amdgcn_mfma_f32_16x16x32_bf16(pB, ones, accl[1], 0, 0, 0);
    };

    for (int c = 0; c < NCHUNK; ++c) {
        const bool more = (c + 2 < NCHUNK);
        if (more) stage(c + 2, (c + 2) % 3);
        compute(c, c % 3);
        if (more) { WAITVM(3); } else { WAITVM(0); }
        __builtin_amdgcn_s_barrier();           // raw rendezvous: NO vmcnt(0) drain
        __builtin_amdgcn_sched_barrier(0);      // keep next chunk's ds_reads below
    }

    float bc[4];
#pragma unroll
    for (int ct = 0; ct < 4; ++ct) bc[ct] = bias[h * FH_ + ct * 16 + m];

#pragma unroll
    for (int r = 0; r < 4; ++r) {
        float inv = 1.0f / (accl[0][r] + accl[1][r]);   // row sum (all cols identical)
        int gr = rowtile + wave * 16 + q * 4 + r;
#pragma unroll
        for (int ct = 0; ct < 4; ++ct) {
            float v = (acc[0][ct][r] + acc[1][ct][r]) * inv + bc[ct];
            out[((size_t)(b * N_) + gr) * C_ + h * FH_ + ct * 16 + m] = fmaxf(v, 0.0f);
        }
    }
}

extern "C" void kernel_launch(void* const* d_in, const int* in_sizes, int n_in,
                              void* d_out, int out_size, void* d_ws, size_t ws_size,
                              hipStream_t stream) {
    const float* X       = (const float*)d_in[0];
    const float* A       = (const float*)d_in[1];
    const float* W       = (const float*)d_in[2];
    const float* bias    = (const float*)d_in[3];
    const float* a_self  = (const float*)d_in[4];
    const float* a_neigh = (const float*)d_in[5];
    float* out = (float*)d_out;   // reference output dtype is float32

    char* ws = (char*)d_ws;
    __hip_bfloat16* featsT = (__hip_bfloat16*)(ws);             // 8 MB   [B][H][FH][N]
    __hip_bfloat16* WT     = (__hip_bfloat16*)(ws + 8388608);   // 32 KB  [H][FH][F]
    float* ss              = (float*)(ws + 8421376);            // 256 KB [B][H][N]
    float* sn              = (float*)(ws + 8683520);            // 256 KB [B][H][N]
    unsigned long long* Am = (unsigned long long*)(ws + 8945664); // 4 MB bitmask

    k0_wt    <<<64, 256, 0, stream>>>(W, WT);
    kp_pack  <<<B_ * N_ / 4, 256, 0, stream>>>(A, Am);
    k1_feats <<<dim3(N_ / 64, H_, B_), 256, 0, stream>>>(X, WT, a_self, a_neigh, featsT, ss, sn);
    k3_attn  <<<dim3(N_ / 64, H_, B_), 256, 0, stream>>>((const unsigned int*)Am, featsT, ss, sn, bias, out);
}

// Round 15
// 252.336 us; speedup vs baseline: 1.1407x; 1.0944x over previous
//
#include <hip/hip_runtime.h>
#include <hip/hip_bf16.h>
#include <stdint.h>

#define B_ 8
#define N_ 2048
#define F_ 64
#define FH_ 64
#define H_ 4
#define C_ (H_*FH_)
#define CHUNK 64
#define NCHUNK (N_/CHUNK)
#define LOG2E 1.44269504088896340736f

typedef short short8 __attribute__((ext_vector_type(8)));   // 8 bf16 raw bits (4 VGPRs)
typedef float f32x4 __attribute__((ext_vector_type(4)));

// float -> bf16 raw bits (RNE)
__device__ __forceinline__ short f2bf(float f) {
    __hip_bfloat16 h = __float2bfloat16(f);
    return __builtin_bit_cast(short, h);
}

// async global->LDS DMA (the only prefetch the compiler cannot sink: R7-R11)
__device__ __forceinline__ void async16(void* l, const void* g) {
    __builtin_amdgcn_global_load_lds((const __attribute__((address_space(1))) unsigned int*)g,
                                     (__attribute__((address_space(3))) unsigned int*)l, 16, 0, 0);
}
__device__ __forceinline__ void async4(void* l, const void* g) {
    __builtin_amdgcn_global_load_lds((const __attribute__((address_space(1))) unsigned int*)g,
                                     (__attribute__((address_space(3))) unsigned int*)l, 4, 0, 0);
}

// ---------------- KF: fused [k1 feats+scores | kp mask-pack] ----------------
// Blocks [0,1024): k1 (featsT + ss/sn, W transposed in-LDS -- k0 eliminated).
// Blocks [1024,5120): kp (A -> 1-bit mask). The two parts are independent; fusing
// them lets the ~21 us HBM-bound A read overlap the ~15 us k1 instead of serializing.
__global__ __launch_bounds__(256) void kf(const float* __restrict__ A,
                                          const float* __restrict__ X,
                                          const float* __restrict__ W,
                                          const float* __restrict__ a_self,
                                          const float* __restrict__ a_neigh,
                                          unsigned long long* __restrict__ Amask,
                                          __hip_bfloat16* __restrict__ featsT,
                                          float* __restrict__ ss,
                                          float* __restrict__ sn) {
    __shared__ float a_lds[2][FH_];
    __shared__ __hip_bfloat16 cw_lds[FH_ * 72];    // W^T (bf16) during MFMA, then C
    const int bx = blockIdx.x;
    const int tid = threadIdx.x;
    const int wave = tid >> 6, lane = tid & 63;

    if (bx >= 1024) {
        // ---------------- kp part ----------------
        const int R = (bx - 1024) * 4 + wave;      // global row 0..16383 (= b*N + i)
        const float* arow = A + (size_t)R * N_;
        unsigned long long* mrow = Amask + (size_t)R * (N_ / 64);
#pragma unroll
        for (int i = 0; i < 8; ++i) {              // 8 x 256 cols
            float a0 = arow[i * 256 + lane];
            float a1 = arow[i * 256 + 64 + lane];
            float a2 = arow[i * 256 + 128 + lane];
            float a3 = arow[i * 256 + 192 + lane];
            unsigned long long m0 = __ballot(a0 != 0.0f);
            unsigned long long m1 = __ballot(a1 != 0.0f);
            unsigned long long m2 = __ballot(a2 != 0.0f);
            unsigned long long m3 = __ballot(a3 != 0.0f);
            if (lane == 0) {
                mrow[i * 4 + 0] = m0; mrow[i * 4 + 1] = m1;
                mrow[i * 4 + 2] = m2; mrow[i * 4 + 3] = m3;
            }
        }
        return;
    }

    // ---------------- k1 part ----------------
    const int nb = bx & 31, h = (bx >> 5) & 3, b = bx >> 7;

    if (tid < 64)       a_lds[0][tid] = a_self[h * FH_ + tid];
    else if (tid < 128) a_lds[1][tid - 64] = a_neigh[h * FH_ + tid - 64];
    {   // stage W[h] transposed to bf16: cw_lds[o*72+f] = bf16(W[h][f][o])
        int f = tid >> 2, o0 = (tid & 3) * 16;
        const float* wsrc = W + ((size_t)(h * F_ + f)) * FH_ + o0;
#pragma unroll
        for (int k = 0; k < 16; ++k)
            cw_lds[(o0 + k) * 72 + f] = __float2bfloat16(wsrc[k]);
    }
    __syncthreads();

    const int m = lane & 15, q = lane >> 4;
    const int nl = wave * 16 + m;               // local column 0..63
    const int n = nb * 64 + nl;                 // B-frag column (node index)
    f32x4 acc[4] = {};
#pragma unroll
    for (int ks = 0; ks < 2; ++ks) {            // K = F = 64, two steps of 32
        const float* xp = X + ((size_t)(b * N_ + n)) * F_ + ks * 32 + q * 8;
        float4 x0 = *(const float4*)xp;
        float4 x1 = *(const float4*)(xp + 4);
        short8 bfrag;
        bfrag[0] = f2bf(x0.x); bfrag[1] = f2bf(x0.y);
        bfrag[2] = f2bf(x0.z); bfrag[3] = f2bf(x0.w);
        bfrag[4] = f2bf(x1.x); bfrag[5] = f2bf(x1.y);
        bfrag[6] = f2bf(x1.z); bfrag[7] = f2bf(x1.w);
#pragma unroll
        for (int ot = 0; ot < 4; ++ot) {
            short8 afrag = *(const short8*)(cw_lds + (ot * 16 + m) * 72 + ks * 32 + q * 8);
            acc[ot] = __builtin_amdgcn_mfma_f32_16x16x32_bf16(afrag, bfrag, acc[ot], 0, 0, 0);
        }
    }
    __syncthreads();    // all W reads done before C overwrites the buffer
    float ssv = 0.f, snv = 0.f;
#pragma unroll
    for (int ot = 0; ot < 4; ++ot) {
#pragma unroll
        for (int r = 0; r < 4; ++r) {
            int orow = ot * 16 + q * 4 + r;     // C: row=(lane>>4)*4+r, col=lane&15
            float v = acc[ot][r];
            cw_lds[orow * 72 + nl] = __float2bfloat16(v);
            ssv += v * a_lds[0][orow];
            snv += v * a_lds[1][orow];
        }
    }
    ssv += __shfl_xor(ssv, 16); ssv += __shfl_xor(ssv, 32);
    snv += __shfl_xor(snv, 16); snv += __shfl_xor(snv, 32);
    __syncthreads();
    {   // coalesced featsT store: thread t -> feature o = t>>2, 16-col chunk (t&3)
        int o = tid >> 2, c = (tid & 3) * 16;
        const __hip_bfloat16* src = cw_lds + o * 72 + c;
        __hip_bfloat16* dst = featsT + ((size_t)(b * H_ + h) * FH_ + o) * N_ + nb * 64 + c;
        *(uint4*)dst       = *(const uint4*)src;
        *(uint4*)(dst + 8) = *(const uint4*)(src + 8);
    }
    if (lane < 16) {
        size_t idx = ((size_t)(b * H_ + h)) * N_ + n;
        ss[idx] = ssv * LOG2E;
        sn[idx] = snv * LOG2E;
    }
}

// ---------------- K3: DMA-pipelined fused softmax+PV (R12 verbatim) ----------------
// grid (N/64, H, B) = 1024 blocks = 4/CU; block = 1 head, 64 rows; wave owns 16 rows.
// K-loop: 32 chunks of 64 cols; fv chunk (8 KB, XOR-swizzled) + mask chunk (512 B)
// DMA-staged double-buffered; one __syncthreads per chunk; inner loop reads LDS only.
// (R13/R14 drain-free/sched_barrier variants measured SLOWER -- keep this shape.)
__global__ __launch_bounds__(256, 4) void k3_attn(const unsigned int* __restrict__ Amask,
                                                  const __hip_bfloat16* __restrict__ featsT,
                                                  const float* __restrict__ ss,
                                                  const float* __restrict__ sn,
                                                  const float* __restrict__ bias,
                                                  float* __restrict__ out) {
    __shared__ __hip_bfloat16 fv_lds[2][64 * CHUNK];   // 2 x 8 KB, swizzled
    __shared__ unsigned int   mk_lds[2][64 * 2];       // 2 x 512 B
    __shared__ float e1_lds[N_];                       // 8 KB: 2^sn_j
    __shared__ float e2_lds[N_];                       // 8 KB: 2^(0.2 sn_j)

    const int tile = blockIdx.x, h = blockIdx.y, b = blockIdx.z;
    const int tid = threadIdx.x, wave = tid >> 6, lane = tid & 63;
    const int m = lane & 15, q = lane >> 4;
    const int rowtile = tile * 64;

    {   // e-tables: 512 float4 slots, 2 per thread
        const float4* snrow = (const float4*)(sn + ((size_t)(b * H_ + h)) * N_);
        float4* e1v = (float4*)e1_lds;
        float4* e2v = (float4*)e2_lds;
#pragma unroll
        for (int i = 0; i < 2; ++i) {
            int idx = tid + i * 256;
            float4 v = snrow[idx];
            float4 u1, u2;
            u1.x = exp2f(v.x); u1.y = exp2f(v.y); u1.z = exp2f(v.z); u1.w = exp2f(v.w);
            u2.x = exp2f(0.2f * v.x); u2.y = exp2f(0.2f * v.y);
            u2.z = exp2f(0.2f * v.z); u2.w = exp2f(0.2f * v.w);
            e1v[idx] = u1; e2v[idx] = u2;
        }
    }
    const float ssi = ss[((size_t)(b * H_ + h)) * N_ + rowtile + wave * 16 + m];
    const float e1i = exp2f(ssi), e2i = exp2f(0.2f * ssi);

    const __hip_bfloat16* fhead = featsT + ((size_t)(b * H_ + h)) * FH_ * N_;
    const unsigned int* mbase = Amask + ((size_t)(b * N_) + rowtile) * (N_ / 32);

    // stage chunk c into buffer bufi (wave-uniform LDS base + lane*size per HW contract)
    auto stage = [&](int c, int bufi) {
        const int cb = c * CHUNK;
#pragma unroll
        for (int i = 0; i < 2; ++i) {           // fv: 64 feats x 64 cols, 512 16B-units
            int base_unit = i * 256 + wave * 64;
            int unit = base_unit + lane;
            int o = unit >> 3, v = unit & 7;
            int u = v ^ (o & 7);                // XOR swizzle (compute-side conflict-free)
            async16(&fv_lds[bufi][base_unit * 8], fhead + (size_t)o * N_ + cb + u * 8);
        }
        if (wave < 2) {                         // mask: 64 rows x 2 dwords = 128 units
            int base_unit = wave * 64;
            int unit = base_unit + lane;
            int row = unit >> 1, dw = unit & 1;
            async4(&mk_lds[bufi][base_unit], mbase + (size_t)row * (N_ / 32) + (cb >> 5) + dw);
        }
    };

    stage(0, 0);
    __syncthreads();    // drains DMA (vmcnt) + e-table LDS writes

    f32x4 acc[2][4] = {};       // [chain][ct]
    f32x4 accl[2] = {};
    short8 ones;
#pragma unroll
    for (int s = 0; s < 8; ++s) ones[s] = (short)0x3F80;   // bf16 1.0

    for (int c = 0; c < NCHUNK; ++c) {
        const int cur = c & 1;
        if (c + 1 < NCHUNK) stage(c + 1, cur ^ 1);

        const int cg = c * CHUNK;
        // e-tables (broadcast within q-group -> near-free LDS reads)
        float4 eA10 = *(const float4*)(e1_lds + cg + q * 8);
        float4 eA11 = *(const float4*)(e1_lds + cg + q * 8 + 4);
        float4 eB10 = *(const float4*)(e1_lds + cg + 32 + q * 8);
        float4 eB11 = *(const float4*)(e1_lds + cg + 32 + q * 8 + 4);
        float4 eA20 = *(const float4*)(e2_lds + cg + q * 8);
        float4 eA21 = *(const float4*)(e2_lds + cg + q * 8 + 4);
        float4 eB20 = *(const float4*)(e2_lds + cg + 32 + q * 8);
        float4 eB21 = *(const float4*)(e2_lds + cg + 32 + q * 8 + 4);
        // fv fragments: chain A = col-units 0..3 (uA=q), chain B = units 4..7
        short8 fA[4], fB[4];
#pragma unroll
        for (int ct = 0; ct < 4; ++ct) {
            int o = ct * 16 + m;
            fA[ct] = *(const short8*)(fv_lds[cur] + ((o << 3) + (q ^ (o & 7))) * 8);
            fB[ct] = *(const short8*)(fv_lds[cur] + ((o << 3) + ((4 + q) ^ (o & 7))) * 8);
        }
        // mask dwords for this row (broadcast within q-group)
        unsigned int mA = mk_lds[cur][(wave * 16 + m) * 2];
        unsigned int mB = mk_lds[cur][(wave * 16 + m) * 2 + 1];

        float e1A[8] = {eA10.x, eA10.y, eA10.z, eA10.w, eA11.x, eA11.y, eA11.z, eA11.w};
        float e1B[8] = {eB10.x, eB10.y, eB10.z, eB10.w, eB11.x, eB11.y, eB11.z, eB11.w};
        float e2A[8] = {eA20.x, eA20.y, eA20.z, eA20.w, eA21.x, eA21.y, eA21.z, eA21.w};
        float e2B[8] = {eB20.x, eB20.y, eB20.z, eB20.w, eB21.x, eB21.y, eB21.z, eB21.w};

        short8 pA, pB;
#pragma unroll
        for (int s = 0; s < 8; ++s) {
            // exp2(leaky(si+sj)) = max(e1i*e1j, e2i*e2j); adjacency via bit test
            float vA = fmaxf(e1i * e1A[s], e2i * e2A[s]);
            float vB = fmaxf(e1i * e1B[s], e2i * e2B[s]);
            const int bit = q * 8 + s;
            pA[s] = (mA >> bit) & 1 ? f2bf(vA) : (short)0;
            pB[s] = (mB >> bit) & 1 ? f2bf(vB) : (short)0;
        }
#pragma unroll
        for (int ct = 0; ct < 4; ++ct) {
            acc[0][ct] = __builtin_amdgcn_mfma_f32_16x16x32_bf16(pA, fA[ct], acc[0][ct], 0, 0, 0);
            acc[1][ct] = __builtin_amdgcn_mfma_f32_16x16x32_bf16(pB, fB[ct], acc[1][ct], 0, 0, 0);
        }
        accl[0] = __builtin_amdgcn_mfma_f32_16x16x32_bf16(pA, ones, accl[0], 0, 0, 0);
        accl[1] = __builtin_amdgcn_mfma_f32_16x16x32_bf16(pB, ones, accl[1], 0, 0, 0);

        __syncthreads();    // drain next-chunk DMA; release cur buffer
    }

    float bc[4];
#pragma unroll
    for (int ct = 0; ct < 4; ++ct) bc[ct] = bias[h * FH_ + ct * 16 + m];

#pragma unroll
    for (int r = 0; r < 4; ++r) {
        float inv = 1.0f / (accl[0][r] + accl[1][r]);   // row sum (all cols identical)
        int gr = rowtile + wave * 16 + q * 4 + r;
#pragma unroll
        for (int ct = 0; ct < 4; ++ct) {
            float v = (acc[0][ct][r] + acc[1][ct][r]) * inv + bc[ct];
            out[((size_t)(b * N_) + gr) * C_ + h * FH_ + ct * 16 + m] = fmaxf(v, 0.0f);
        }
    }
}

extern "C" void kernel_launch(void* const* d_in, const int* in_sizes, int n_in,
                              void* d_out, int out_size, void* d_ws, size_t ws_size,
                              hipStream_t stream) {
    const float* X       = (const float*)d_in[0];
    const float* A       = (const float*)d_in[1];
    const float* W       = (const float*)d_in[2];
    const float* bias    = (const float*)d_in[3];
    const float* a_self  = (const float*)d_in[4];
    const float* a_neigh = (const float*)d_in[5];
    float* out = (float*)d_out;   // reference output dtype is float32

    char* ws = (char*)d_ws;
    __hip_bfloat16* featsT = (__hip_bfloat16*)(ws);             // 8 MB   [B][H][FH][N]
    float* ss              = (float*)(ws + 8421376);            // 256 KB [B][H][N]
    float* sn              = (float*)(ws + 8683520);            // 256 KB [B][H][N]
    unsigned long long* Am = (unsigned long long*)(ws + 8945664); // 4 MB bitmask

    kf      <<<5120, 256, 0, stream>>>(A, X, W, a_self, a_neigh, Am, featsT, ss, sn);
    k3_attn <<<dim3(N_ / 64, H_, B_), 256, 0, stream>>>((const unsigned int*)Am, featsT, ss, sn, bias, out);
}